// Round 12
// baseline (298.494 us; speedup 1.0000x reference)
//
#include <hip/hip_runtime.h>
#include <stdint.h>

#define DD 64
#define HH 128
#define WW 128
#define NVOX (DD * HH * WW)      // 1<<20
#define NWRD (NVOX / 32)         // 32768 words per mask
#define BATCH 2
#define NCLS 4
#define NMASK 12                 // 6 pred then 6 target
#define NPROB 36                 // phase*12 + m ; phase: 0=mask 1=eroded 2=background
#define NTILE 128                // (HH/8)*(DD/8) tiles of 128x8x8 voxels
#define MAXC 4096                // max components per 8192-voxel tile (checkerboard bound)
#define VNODE (NTILE * MAXC)     // virtual border node id = 524288
#define NODE_STRIDE (VNODE + 64) // ints per component-parent slot
#define NTASKW 7424              // face word-crossings per problem: 3840 y + 3584 z
#define NTASKH (2 * NTASKW)      // half-word crossings

// ---------------- global lock-free union-find (on component ids) --------
__device__ __forceinline__ int uf_find(int* P, int x) {
    while (true) {
        int p = P[x];
        if (p == x) return x;
        int gp = P[p];
        if (gp != p) P[x] = gp;   // path halving (benign race; never demotes a root)
        x = gp;
    }
}
__device__ __forceinline__ int uf_find_ro(const int* P, int x) {
    int p;
    while ((p = P[x]) != x) x = p;
    return x;
}
// counting union: each successful CAS demotes exactly one root -> dec.
__device__ __forceinline__ void uf_union(int* P, int a, int b, int* dec) {
    while (true) {
        a = uf_find(P, a);
        b = uf_find(P, b);
        if (a == b) return;
        int lo = a < b ? a : b;
        int hi = a < b ? b : a;
        int old = atomicCAS(&P[hi], hi, lo);
        if (old == hi) { if (dec) atomicSub(dec, 1); return; }
        a = lo; b = old;
    }
}

// ---------------- LDS union-find on half-word run heads (swizzled) ------
#define SW(v) ((v) + ((v) >> 5))
__device__ __forceinline__ int lfind(int* lp, int x) {
    while (true) {
        int p = lp[SW(x)];
        if (p == x) return x;
        int gp = lp[SW(p)];
        if (gp != p) lp[SW(x)] = gp;
        x = gp;
    }
}
__device__ __forceinline__ void lunion(int* lp, int a, int b) {
    while (true) {
        a = lfind(lp, a);
        b = lfind(lp, b);
        if (a == b) return;
        int lo = a < b ? a : b;
        int hi = a < b ? b : a;
        int old = atomicCAS(&lp[SW(hi)], hi, lo);
        if (old == hi) return;
        a = lo; b = old;
    }
}
// resolve a head to its component's compact id (root entries hold -k-1).
__device__ __forceinline__ int lresolve(const int* lp, int h) {
    int v = lp[SW(h)];
    while (v >= 0) v = lp[SW(v)];
    return -v - 1;
}
// start bit of the 1-run of w containing set bit p (works for 16/32-bit w)
__device__ __forceinline__ int run_head(uint32_t w, int p) {
    uint32_t below = ~w & ((1u << p) - 1u);
    return below ? (32 - __clz((int)below)) : 0;
}

// word loader for problem (phase, m)
__device__ __forceinline__ uint32_t ld_word(const uint32_t* __restrict__ maskW,
                                            const uint32_t* __restrict__ erodW,
                                            int phase, int m, int w) {
    if (phase == 0) return maskW[m * NWRD + w];
    if (phase == 1) return erodW[m * NWRD + w];
    return ~maskW[m * NWRD + w];
}

// tile index of word w (tz*16 + ty)
__device__ __forceinline__ int tile_of_w(int w) {
    int z = w >> 9, y = (w >> 2) & 127;
    return (z >> 3) * 16 + (y >> 3);
}

// ---------------- kernels ----------------

// Build 12 bitpacked masks via ballot; zero counters.
__global__ void k_masks2(const float* __restrict__ pred, const int* __restrict__ tgt,
                         uint32_t* __restrict__ maskW, int* __restrict__ counts) {
    int tid = blockIdx.x * blockDim.x + threadIdx.x;   // 0 .. BATCH*NVOX-1
    if (tid < 64) counts[tid] = 0;
    int b = tid >> 20;
    int i = tid & (NVOX - 1);
    const float* p = pred + (size_t)b * NCLS * NVOX + i;
    float x0 = p[0], x1 = p[NVOX], x2 = p[2 * NVOX], x3 = p[3 * NVOX];
    float mx = fmaxf(fmaxf(x0, x1), fmaxf(x2, x3));
    float e0 = __expf(x0 - mx), e1 = __expf(x1 - mx), e2 = __expf(x2 - mx), e3 = __expf(x3 - mx);
    float S = e0 + e1 + e2 + e3;
    int t = tgt[(size_t)b * NVOX + i];
    int lane = threadIdx.x & 63;
    int wbase = i >> 5;
    float ev[3] = {e1, e2, e3};
    for (int c = 0; c < 3; ++c) {
        unsigned long long bal = __ballot(ev[c] / S > 0.5f);
        uint32_t* M = maskW + (size_t)(b * 3 + c) * NWRD;
        if (lane == 0)  M[wbase] = (uint32_t)bal;
        if (lane == 32) M[wbase] = (uint32_t)(bal >> 32);
        unsigned long long balT = __ballot(t == c + 1);
        uint32_t* MT = maskW + (size_t)(6 + b * 3 + c) * NWRD;
        if (lane == 0)  MT[wbase] = (uint32_t)balT;
        if (lane == 32) MT[wbase] = (uint32_t)(balT >> 32);
    }
}

// 6-conn binary erosion, border_value=0, bitwise.
__global__ void k_erode(const uint32_t* __restrict__ maskW, uint32_t* __restrict__ erodW) {
    int tid = blockIdx.x * blockDim.x + threadIdx.x;   // 0 .. 12*NWRD-1
    int m = tid / NWRD;
    int w = tid - m * NWRD;
    const uint32_t* M = maskW + (size_t)m * NWRD;
    int z = w >> 9, y = (w >> 2) & 127, q = w & 3;
    uint32_t a = M[w];
    uint32_t xl = (a << 1) | (q ? (M[w - 1] >> 31) : 0u);
    uint32_t xr = (a >> 1) | (q < 3 ? (M[w + 1] << 31) : 0u);
    uint32_t ym = (y > 0)   ? M[w - 4]   : 0u;
    uint32_t yp = (y < 127) ? M[w + 4]   : 0u;
    uint32_t zm = (z > 0)   ? M[w - 512] : 0u;
    uint32_t zp = (z < 63)  ? M[w + 512] : 0u;
    erodW[tid] = a & xl & xr & ym & yp & zm & zp;
}

// Tile-local CC (128x8x8 per block, 512 threads = one per 16-bit half-word):
// head-only LDS union-find, compact id allocation, demand-driven C16 emit,
// phase-2 border pre-link to VNODE.
__global__ void k_local(const uint32_t* __restrict__ maskW, const uint32_t* __restrict__ erodW,
                        uint16_t* __restrict__ C16all, int* __restrict__ Pall,
                        int* __restrict__ counts, int* __restrict__ tcount, int m0) {
    __shared__ int lp[8448];         // swizzled; only half-run-head entries live
    __shared__ int lcount;
    int slot = blockIdx.y;
    int pr = m0 + slot;
    int phase = pr / 12, m = pr % 12;
    uint16_t* C16 = C16all + (size_t)slot * NVOX;
    int* P = Pall + (size_t)slot * NODE_STRIDE;
    int tile = blockIdx.x;                         // 0..127
    int tz = tile >> 4, ty = tile & 15;
    int t2 = threadIdx.x;                          // 0..511 : half-word index
    int wl = t2 >> 1;                              // local word 0..255
    int h  = t2 & 1;                               // half within word
    int zl = wl >> 5, yl = (wl >> 2) & 7, q = wl & 3;
    int gw = ((tz * 8 + zl) * 128 + (ty * 8 + yl)) * 4 + q;
    uint32_t afull = ld_word(maskW, erodW, phase, m, gw);
    uint32_t a16 = (afull >> (16 * h)) & 0xFFFFu;
    if (t2 == 0) lcount = 0;
    if (blockIdx.x == 0 && t2 == 0) P[VNODE] = VNODE;   // virtual border node

    // s1: init half-run-head entries only
    int lbase = t2 << 4;
    uint32_t heads = a16 & ~(a16 << 1) & 0xFFFFu;
    {
        uint32_t st = heads;
        while (st) { int p = __ffs(st) - 1; st &= st - 1; lp[SW(lbase + p)] = lbase + p; }
    }
    __syncthreads();

    // s2: intra-tile unions (half-head nodes; neighbor heads arithmetic)
    if (a16) {
        if (a16 & 1u) {            // x link to previous half / previous word
            if (h == 1) {
                uint32_t lo16 = afull & 0xFFFFu;
                if (lo16 >> 15) lunion(lp, lbase, lbase - 16 + run_head(lo16, 15));
            } else if (q) {
                uint32_t hi16 = ld_word(maskW, erodW, phase, m, gw - 1) >> 16;
                if (hi16 >> 15) lunion(lp, lbase, lbase - 16 + run_head(hi16, 15));
            }
        }
        if (yl < 7) {
            uint32_t by = (ld_word(maskW, erodW, phase, m, gw + 4) >> (16 * h)) & 0xFFFFu;
            uint32_t ov = a16 & by;
            uint32_t st = ov & ~(ov << 1);
            int la = -1, lb = -1;
            while (st) {
                int p = __ffs(st) - 1; st &= st - 1;
                int ha = lbase + run_head(a16, p);
                int hb = lbase + 128 + run_head(by, p);     // word+4 -> +8 halves
                if (ha != la || hb != lb) { lunion(lp, ha, hb); la = ha; lb = hb; }
            }
        }
        if (zl < 7) {
            uint32_t bz = (ld_word(maskW, erodW, phase, m, gw + 512) >> (16 * h)) & 0xFFFFu;
            uint32_t ov = a16 & bz;
            uint32_t st = ov & ~(ov << 1);
            int la = -1, lb = -1;
            while (st) {
                int p = __ffs(st) - 1; st &= st - 1;
                int ha = lbase + run_head(a16, p);
                int hb = lbase + 1024 + run_head(bz, p);    // word+32 -> +64 halves
                if (ha != la || hb != lb) { lunion(lp, ha, hb); la = ha; lb = hb; }
            }
        }
    }
    __syncthreads();

    // s3: root heads allocate compact ids (root entry := -k-1)
    int tileBase = tile * MAXC;
    {
        uint32_t st = heads;
        while (st) {
            int p = __ffs(st) - 1; st &= st - 1;
            int hh = lbase + p;
            if (lp[SW(hh)] == hh) {
                int k = atomicAdd(&lcount, 1);
                lp[SW(hh)] = -k - 1;
                P[tileBase + k] = tileBase + k;    // sparse parent init
            }
        }
    }
    __syncthreads();

    if (t2 == 0) {
        tcount[slot * NTILE + tile] = lcount;
        if (phase < 2 && lcount) atomicAdd(&counts[pr], lcount);
    }

    // s4: demand-driven emit + phase-2 VNODE pre-link.
    bool faceRow = (yl == 0 || yl == 7 || zl == 0 || zl == 7);
    if (a16 && (phase == 2 || faceRow)) {
        int i0 = (gw << 5) + 16 * h;
        int gz = tz * 8 + zl, gy = ty * 8 + yl;
        bool bordRow = (phase == 2) && (gz == 0 || gz == 63 || gy == 0 || gy == 127);
        if (faceRow && a16 == 0xFFFFu) {
            int id = lresolve(lp, lbase);
            uint32_t pk = (uint32_t)id * 0x10001u;
            uint4 v = make_uint4(pk, pk, pk, pk);
            uint4* dst = (uint4*)(C16 + i0);
            dst[0] = v; dst[1] = v;
            if (phase == 2 && (bordRow || (q == 0 && h == 0) || (q == 3 && h == 1)))
                P[tileBase + id] = VNODE;
        } else {
            int htop = (a16 >> 15) ? run_head(a16, 15) : -1;
            uint32_t st = heads;
            while (st) {
                int p = __ffs(st) - 1; st &= st - 1;
                int id = lresolve(lp, lbase + p);
                C16[i0 + p] = (uint16_t)id;
                if (faceRow) {
                    uint32_t run = a16 >> p;
                    int len = __ffs(~run) - 1;       // run < 2^16 so ~run != 0
                    for (int j = 1; j < len; ++j) C16[i0 + p + j] = (uint16_t)id;
                }
                if (phase == 2 &&
                    (bordRow || (q == 0 && h == 0 && p == 0) ||
                     (q == 3 && h == 1 && p == htop)))
                    P[tileBase + id] = VNODE;
            }
        }
    }
}

// face merges: one thread per face HALF-WORD crossing. All independent loads
// (two mask words + the two C16 row lines, whose addresses depend only on w)
// are issued up-front in parallel -> serial chain depth 2 instead of 4.
// Cross-half/word duplicate unions are idempotent and exactly counted.
__global__ void k_bmerge(const uint32_t* __restrict__ maskW, const uint32_t* __restrict__ erodW,
                         const uint16_t* __restrict__ C16all, int* __restrict__ Pall,
                         int* __restrict__ counts, int m0) {
    int t = blockIdx.x * blockDim.x + threadIdx.x;     // 0 .. NTASKH-1 (padded)
    int slot = blockIdx.y;
    int pr = m0 + slot;
    int phase = pr / 12, m = pr % 12;
    int c = t >> 1, h = t & 1;
    bool act = (c < NTASKW);
    if (!act) c = 0;                                   // safe dummy task

    int w, dw, dv, tA, tB;
    if (c < 3840) {                     // y-face: yi in 0..14, z in 0..63, q in 0..3
        int q = c & 3, r = c >> 2;
        int yi = r >> 6, z = r & 63;
        int y = 8 * yi + 7;
        w = (z * 128 + y) * 4 + q;
        dw = 4; dv = WW;
        tA = ((z >> 3) * 16 + yi) * MAXC;
        tB = tA + MAXC;
    } else {                            // z-face: zi in 0..6, y in 0..127, q in 0..3
        int tt = c - 3840;
        int q = tt & 3, r = tt >> 2;
        int zi = r >> 7, y = r & 127;
        int z = 8 * zi + 7;
        w = (z * 128 + y) * 4 + q;
        dw = 512; dv = HH * WW;
        tA = (zi * 16 + (y >> 3)) * MAXC;
        tB = tA + 16 * MAXC;
    }

    const uint16_t* C16 = C16all + (size_t)slot * NVOX;
    int i0 = (w << 5) + 16 * h;
    // --- all independent: issued before any wait ---
    uint32_t aw = ld_word(maskW, erodW, phase, m, w);
    uint32_t bw = ld_word(maskW, erodW, phase, m, w + dw);
    int c0a = C16[i0];                  // warms the 64B C16 row line
    int c0b = C16[i0 + dv];             // warms the partner row line
    // -----------------------------------------------
    uint32_t a16 = (aw >> (16 * h)) & 0xFFFFu;
    uint32_t b16 = (bw >> (16 * h)) & 0xFFFFu;
    uint32_t ov = act ? (a16 & b16) : 0u;
    uint32_t st = ov & ~(ov << 1);

    int ca = -1, cb = -1, p0 = -1;
    if (st) {
        p0 = __ffs(st) - 1;
        ca = tA + (p0 == 0 ? c0a : (int)C16[i0 + p0]);
        cb = tB + (p0 == 0 ? c0b : (int)C16[i0 + p0 + dv]);
    }
    // cross-lane dedup seed: previous lane's first pair
    int la = __shfl_up(ca, 1);
    int lb = __shfl_up(cb, 1);
    if ((threadIdx.x & 63) == 0) { la = -1; lb = -1; }
    if (!st) return;

    int* P = Pall + (size_t)slot * NODE_STRIDE;
    int* dec = (phase < 2) ? &counts[pr] : (int*)0;
    while (st) {
        int p = __ffs(st) - 1; st &= st - 1;
        int xa, xb;
        if (p == p0) { xa = ca; xb = cb; }
        else { xa = tA + C16[i0 + p]; xb = tB + C16[i0 + p + dv]; }   // L1-hot
        if (xa != la || xb != lb) { uf_union(P, xa, xb, dec); la = xa; lb = xb; }
    }
}

// flatten allocated component entries (phase-2 slots) so finds become 1 load.
__global__ void k_flat(int* __restrict__ Pall, const int* __restrict__ tcount, int slot0) {
    int slot = slot0 + blockIdx.y;
    int tile = blockIdx.x;
    int* P = Pall + (size_t)slot * NODE_STRIDE;
    int lc = tcount[slot * NTILE + tile];
    for (int k = threadIdx.x; k < lc; k += blockDim.x) {
        int id = tile * MAXC + k;
        P[id] = uf_find_ro(P, id);
    }
    if (tile == 0 && threadIdx.x == 0) P[VNODE] = uf_find_ro(P, VNODE);
}

// phase 2: cavity volume = bg voxels whose component != border component.
__global__ void k_count2(const uint32_t* __restrict__ maskW,
                         const uint16_t* __restrict__ C16all, const int* __restrict__ Pall,
                         int* __restrict__ counts, int pr0, int slot0) {
    __shared__ int sRootV;
    int w = blockIdx.x * blockDim.x + threadIdx.x;
    int slot = slot0 + blockIdx.y;
    int pr = pr0 + blockIdx.y;
    int m = pr % 12;
    const uint16_t* C16 = C16all + (size_t)slot * NVOX;
    const int* P = Pall + (size_t)slot * NODE_STRIDE;
    if (threadIdx.x == 0) sRootV = P[VNODE];           // flattened
    __syncthreads();
    int i0 = w << 5;
    // independent loads up-front: mask word + C16 row-line warm
    uint32_t a = ~maskW[m * NWRD + w];
    int c0 = C16[i0];
    int cnt = 0;
    if (a) {
        int tA = tile_of_w(w) * MAXC;
        int rootV = sRootV;
        uint32_t st = a & ~(a << 1);
        while (st) {
            int p = __ffs(st) - 1; st &= st - 1;
            uint32_t run = a >> p;
            uint32_t inv = ~run;
            int len = inv ? (__ffs(inv) - 1) : (32 - p);
            int id = (p == 0) ? c0 : (int)C16[i0 + p];     // L1-hot line
            if (P[tA + id] != rootV) cnt += len;           // flattened: 1 load
        }
    }
    for (int off = 32; off; off >>= 1) cnt += __shfl_down(cnt, off);
    if ((threadIdx.x & 63) == 0 && cnt) atomicAdd(&counts[pr], cnt);
}

__global__ void k_loss(const int* __restrict__ counts, float* __restrict__ out) {
    if (threadIdx.x != 0 || blockIdx.x != 0) return;
    float acc = 0.f;
    for (int m = 0; m < 6; ++m) {
        int pb0 = counts[m],      pbe = counts[12 + m],      pcv = counts[24 + m];
        int tb0 = counts[6 + m],  tbe = counts[12 + 6 + m],  tcv = counts[24 + 6 + m];
        int pb1 = max(0, pb0 - pbe), tb1 = max(0, tb0 - tbe);
        int pb2 = pcv / 100, tb2 = tcv / 100;
        acc += fabsf((float)(pb0 - tb0)) + fabsf((float)(pb1 - tb1)) + fabsf((float)(pb2 - tb2));
    }
    out[0] = 0.1f * acc / 6.0f;
}

// ---------------- launch ----------------
extern "C" void kernel_launch(void* const* d_in, const int* in_sizes, int n_in,
                              void* d_out, int out_size, void* d_ws, size_t ws_size,
                              hipStream_t stream) {
    const float* pred = (const float*)d_in[0];
    const int* tgt = (const int*)d_in[1];
    float* out = (float*)d_out;

    uint8_t* ws = (uint8_t*)d_ws;
    uint32_t* maskW = (uint32_t*)ws;
    size_t off = (size_t)NMASK * NWRD * 4;                 // 1.5 MB
    uint32_t* erodW = (uint32_t*)(ws + off);
    off += (size_t)NMASK * NWRD * 4;                       // +1.5 MB
    int* counts = (int*)(ws + off);
    off += 256;
    int* tcount = (int*)(ws + off);
    off += (size_t)NPROB * NTILE * 4;                      // 18 KB
    off = (off + 255) & ~(size_t)255;

    size_t avail = ws_size > off ? ws_size - off : 0;
    size_t slot_bytes = (size_t)NVOX * 2 + (size_t)NODE_STRIDE * 4;  // ~4.2 MB
    int PB = (int)(avail / slot_bytes);
    if (PB > NPROB) PB = NPROB;
    if (PB < 1) PB = 1;

    uint16_t* C16all = (uint16_t*)(ws + off);
    int* Pall = (int*)(ws + off + (size_t)PB * NVOX * 2);

    k_masks2<<<dim3((BATCH * NVOX) / 256), 256, 0, stream>>>(pred, tgt, maskW, counts);
    k_erode<<<dim3((NMASK * NWRD) / 256), 256, 0, stream>>>(maskW, erodW);

    for (int m0 = 0; m0 < NPROB; m0 += PB) {
        int mb = PB < (NPROB - m0) ? PB : (NPROB - m0);
        k_local <<<dim3(NTILE, mb), 512, 0, stream>>>(maskW, erodW, C16all, Pall,
                                                      counts, tcount, m0);
        k_bmerge<<<dim3((NTASKH + 255) / 256, mb), 256, 0, stream>>>(maskW, erodW, C16all,
                                                                     Pall, counts, m0);
        int lo2 = m0 > 24 ? m0 : 24;
        int n2 = (m0 + mb) - lo2;
        if (n2 > 0) {
            k_flat  <<<dim3(NTILE, n2), 256, 0, stream>>>(Pall, tcount, lo2 - m0);
            k_count2<<<dim3(NWRD / 256, n2), 256, 0, stream>>>(maskW, C16all, Pall, counts,
                                                               lo2, lo2 - m0);
        }
    }

    k_loss<<<1, 64, 0, stream>>>(counts, out);
}

// Round 13
// 298.120 us; speedup vs baseline: 1.0013x; 1.0013x over previous
//
#include <hip/hip_runtime.h>
#include <stdint.h>

#define DD 64
#define HH 128
#define WW 128
#define NVOX (DD * HH * WW)      // 1<<20
#define NWRD (NVOX / 32)         // 32768 words per mask
#define BATCH 2
#define NCLS 4
#define NMASK 12                 // 6 pred then 6 target
#define NPROB 36                 // phase*12 + m ; phase: 0=mask 1=eroded 2=background
#define NTILE 128                // (HH/8)*(DD/8) tiles of 128x8x8 voxels
#define MAXC 4096                // max components per 8192-voxel tile (checkerboard bound)
#define VNODE (NTILE * MAXC)     // virtual border node id = 524288
#define NODE_STRIDE (VNODE + 64) // ints per component-parent slot
#define NTASKW 7424              // face word-crossings per problem: 3840 y + 3584 z
#define NTASKH (2 * NTASKW)      // half-word crossings = 14848 = 58 * 256

// ---------------- global lock-free union-find (on component ids) --------
__device__ __forceinline__ int uf_find(int* P, int x) {
    while (true) {
        int p = P[x];
        if (p == x) return x;
        int gp = P[p];
        if (gp != p) P[x] = gp;   // path halving (benign race; never demotes a root)
        x = gp;
    }
}
__device__ __forceinline__ int uf_find_ro(const int* P, int x) {
    int p;
    while ((p = P[x]) != x) x = p;
    return x;
}
// counting union: each successful CAS demotes exactly one root -> dec.
__device__ __forceinline__ void uf_union(int* P, int a, int b, int* dec) {
    while (true) {
        a = uf_find(P, a);
        b = uf_find(P, b);
        if (a == b) return;
        int lo = a < b ? a : b;
        int hi = a < b ? b : a;
        int old = atomicCAS(&P[hi], hi, lo);
        if (old == hi) { if (dec) atomicSub(dec, 1); return; }
        a = lo; b = old;
    }
}

// ---------------- LDS union-find on half-word run heads (swizzled) ------
#define SW(v) ((v) + ((v) >> 5))
__device__ __forceinline__ int lfind(int* lp, int x) {
    while (true) {
        int p = lp[SW(x)];
        if (p == x) return x;
        int gp = lp[SW(p)];
        if (gp != p) lp[SW(x)] = gp;
        x = gp;
    }
}
__device__ __forceinline__ void lunion(int* lp, int a, int b) {
    while (true) {
        a = lfind(lp, a);
        b = lfind(lp, b);
        if (a == b) return;
        int lo = a < b ? a : b;
        int hi = a < b ? b : a;
        int old = atomicCAS(&lp[SW(hi)], hi, lo);
        if (old == hi) return;
        a = lo; b = old;
    }
}
// resolve a head to its component's compact id (root entries hold -k-1).
__device__ __forceinline__ int lresolve(const int* lp, int h) {
    int v = lp[SW(h)];
    while (v >= 0) v = lp[SW(v)];
    return -v - 1;
}
// start bit of the 1-run of w containing set bit p (works for 16/32-bit w)
__device__ __forceinline__ int run_head(uint32_t w, int p) {
    uint32_t below = ~w & ((1u << p) - 1u);
    return below ? (32 - __clz((int)below)) : 0;
}

// word loader for problem (phase, m)
__device__ __forceinline__ uint32_t ld_word(const uint32_t* __restrict__ maskW,
                                            const uint32_t* __restrict__ erodW,
                                            int phase, int m, int w) {
    if (phase == 0) return maskW[m * NWRD + w];
    if (phase == 1) return erodW[m * NWRD + w];
    return ~maskW[m * NWRD + w];
}

// tile index of word w (tz*16 + ty)
__device__ __forceinline__ int tile_of_w(int w) {
    int z = w >> 9, y = (w >> 2) & 127;
    return (z >> 3) * 16 + (y >> 3);
}

// ---------------- kernels ----------------

// Build 12 bitpacked masks via ballot; zero counters.
__global__ void k_masks2(const float* __restrict__ pred, const int* __restrict__ tgt,
                         uint32_t* __restrict__ maskW, int* __restrict__ counts) {
    int tid = blockIdx.x * blockDim.x + threadIdx.x;   // 0 .. BATCH*NVOX-1
    if (tid < 64) counts[tid] = 0;
    int b = tid >> 20;
    int i = tid & (NVOX - 1);
    const float* p = pred + (size_t)b * NCLS * NVOX + i;
    float x0 = p[0], x1 = p[NVOX], x2 = p[2 * NVOX], x3 = p[3 * NVOX];
    float mx = fmaxf(fmaxf(x0, x1), fmaxf(x2, x3));
    float e0 = __expf(x0 - mx), e1 = __expf(x1 - mx), e2 = __expf(x2 - mx), e3 = __expf(x3 - mx);
    float S = e0 + e1 + e2 + e3;
    int t = tgt[(size_t)b * NVOX + i];
    int lane = threadIdx.x & 63;
    int wbase = i >> 5;
    float ev[3] = {e1, e2, e3};
    for (int c = 0; c < 3; ++c) {
        unsigned long long bal = __ballot(ev[c] / S > 0.5f);
        uint32_t* M = maskW + (size_t)(b * 3 + c) * NWRD;
        if (lane == 0)  M[wbase] = (uint32_t)bal;
        if (lane == 32) M[wbase] = (uint32_t)(bal >> 32);
        unsigned long long balT = __ballot(t == c + 1);
        uint32_t* MT = maskW + (size_t)(6 + b * 3 + c) * NWRD;
        if (lane == 0)  MT[wbase] = (uint32_t)balT;
        if (lane == 32) MT[wbase] = (uint32_t)(balT >> 32);
    }
}

// 6-conn binary erosion, border_value=0, bitwise.
__global__ void k_erode(const uint32_t* __restrict__ maskW, uint32_t* __restrict__ erodW) {
    int tid = blockIdx.x * blockDim.x + threadIdx.x;   // 0 .. 12*NWRD-1
    int m = tid / NWRD;
    int w = tid - m * NWRD;
    const uint32_t* M = maskW + (size_t)m * NWRD;
    int z = w >> 9, y = (w >> 2) & 127, q = w & 3;
    uint32_t a = M[w];
    uint32_t xl = (a << 1) | (q ? (M[w - 1] >> 31) : 0u);
    uint32_t xr = (a >> 1) | (q < 3 ? (M[w + 1] << 31) : 0u);
    uint32_t ym = (y > 0)   ? M[w - 4]   : 0u;
    uint32_t yp = (y < 127) ? M[w + 4]   : 0u;
    uint32_t zm = (z > 0)   ? M[w - 512] : 0u;
    uint32_t zp = (z < 63)  ? M[w + 512] : 0u;
    erodW[tid] = a & xl & xr & ym & yp & zm & zp;
}

// Tile-local CC (128x8x8 per block, 512 threads = one per 16-bit half-word):
// head-only LDS union-find, compact id allocation, demand-driven C16 emit,
// phase-2 border pre-link to VNODE.
__global__ void k_local(const uint32_t* __restrict__ maskW, const uint32_t* __restrict__ erodW,
                        uint16_t* __restrict__ C16all, int* __restrict__ Pall,
                        int* __restrict__ counts, int* __restrict__ tcount, int m0) {
    __shared__ int lp[8448];         // swizzled; only half-run-head entries live
    __shared__ int lcount;
    int slot = blockIdx.y;
    int pr = m0 + slot;
    int phase = pr / 12, m = pr % 12;
    uint16_t* C16 = C16all + (size_t)slot * NVOX;
    int* P = Pall + (size_t)slot * NODE_STRIDE;
    int tile = blockIdx.x;                         // 0..127
    int tz = tile >> 4, ty = tile & 15;
    int t2 = threadIdx.x;                          // 0..511 : half-word index
    int wl = t2 >> 1;                              // local word 0..255
    int h  = t2 & 1;                               // half within word
    int zl = wl >> 5, yl = (wl >> 2) & 7, q = wl & 3;
    int gw = ((tz * 8 + zl) * 128 + (ty * 8 + yl)) * 4 + q;
    uint32_t afull = ld_word(maskW, erodW, phase, m, gw);
    uint32_t a16 = (afull >> (16 * h)) & 0xFFFFu;
    if (t2 == 0) lcount = 0;
    if (blockIdx.x == 0 && t2 == 0) P[VNODE] = VNODE;   // virtual border node

    // s1: init half-run-head entries only
    int lbase = t2 << 4;
    uint32_t heads = a16 & ~(a16 << 1) & 0xFFFFu;
    {
        uint32_t st = heads;
        while (st) { int p = __ffs(st) - 1; st &= st - 1; lp[SW(lbase + p)] = lbase + p; }
    }
    __syncthreads();

    // s2: intra-tile unions (half-head nodes; neighbor heads arithmetic)
    if (a16) {
        if (a16 & 1u) {            // x link to previous half / previous word
            if (h == 1) {
                uint32_t lo16 = afull & 0xFFFFu;
                if (lo16 >> 15) lunion(lp, lbase, lbase - 16 + run_head(lo16, 15));
            } else if (q) {
                uint32_t hi16 = ld_word(maskW, erodW, phase, m, gw - 1) >> 16;
                if (hi16 >> 15) lunion(lp, lbase, lbase - 16 + run_head(hi16, 15));
            }
        }
        if (yl < 7) {
            uint32_t by = (ld_word(maskW, erodW, phase, m, gw + 4) >> (16 * h)) & 0xFFFFu;
            uint32_t ov = a16 & by;
            uint32_t st = ov & ~(ov << 1);
            int la = -1, lb = -1;
            while (st) {
                int p = __ffs(st) - 1; st &= st - 1;
                int ha = lbase + run_head(a16, p);
                int hb = lbase + 128 + run_head(by, p);     // word+4 -> +8 halves
                if (ha != la || hb != lb) { lunion(lp, ha, hb); la = ha; lb = hb; }
            }
        }
        if (zl < 7) {
            uint32_t bz = (ld_word(maskW, erodW, phase, m, gw + 512) >> (16 * h)) & 0xFFFFu;
            uint32_t ov = a16 & bz;
            uint32_t st = ov & ~(ov << 1);
            int la = -1, lb = -1;
            while (st) {
                int p = __ffs(st) - 1; st &= st - 1;
                int ha = lbase + run_head(a16, p);
                int hb = lbase + 1024 + run_head(bz, p);    // word+32 -> +64 halves
                if (ha != la || hb != lb) { lunion(lp, ha, hb); la = ha; lb = hb; }
            }
        }
    }
    __syncthreads();

    // s3: root heads allocate compact ids (root entry := -k-1)
    int tileBase = tile * MAXC;
    {
        uint32_t st = heads;
        while (st) {
            int p = __ffs(st) - 1; st &= st - 1;
            int hh = lbase + p;
            if (lp[SW(hh)] == hh) {
                int k = atomicAdd(&lcount, 1);
                lp[SW(hh)] = -k - 1;
                P[tileBase + k] = tileBase + k;    // sparse parent init
            }
        }
    }
    __syncthreads();

    if (t2 == 0) {
        tcount[slot * NTILE + tile] = lcount;
        if (phase < 2 && lcount) atomicAdd(&counts[pr], lcount);
    }

    // s4: demand-driven emit + phase-2 VNODE pre-link.
    bool faceRow = (yl == 0 || yl == 7 || zl == 0 || zl == 7);
    if (a16 && (phase == 2 || faceRow)) {
        int i0 = (gw << 5) + 16 * h;
        int gz = tz * 8 + zl, gy = ty * 8 + yl;
        bool bordRow = (phase == 2) && (gz == 0 || gz == 63 || gy == 0 || gy == 127);
        if (faceRow && a16 == 0xFFFFu) {
            int id = lresolve(lp, lbase);
            uint32_t pk = (uint32_t)id * 0x10001u;
            uint4 v = make_uint4(pk, pk, pk, pk);
            uint4* dst = (uint4*)(C16 + i0);
            dst[0] = v; dst[1] = v;
            if (phase == 2 && (bordRow || (q == 0 && h == 0) || (q == 3 && h == 1)))
                P[tileBase + id] = VNODE;
        } else {
            int htop = (a16 >> 15) ? run_head(a16, 15) : -1;
            uint32_t st = heads;
            while (st) {
                int p = __ffs(st) - 1; st &= st - 1;
                int id = lresolve(lp, lbase + p);
                C16[i0 + p] = (uint16_t)id;
                if (faceRow) {
                    uint32_t run = a16 >> p;
                    int len = __ffs(~run) - 1;       // run < 2^16 so ~run != 0
                    for (int j = 1; j < len; ++j) C16[i0 + p + j] = (uint16_t)id;
                }
                if (phase == 2 &&
                    (bordRow || (q == 0 && h == 0 && p == 0) ||
                     (q == 3 && h == 1 && p == htop)))
                    P[tileBase + id] = VNODE;
            }
        }
    }
}

// face merges: one thread per face HALF-WORD crossing (2x tail parallelism vs
// word tasks), with strictly CONDITIONAL loads: mask word first (L2-hot;
// sparse phases exit here), partner word only if live, C16 only per head.
// Cross-half/word duplicate unions are idempotent and exactly counted.
__global__ void k_bmerge(const uint32_t* __restrict__ maskW, const uint32_t* __restrict__ erodW,
                         const uint16_t* __restrict__ C16all, int* __restrict__ Pall,
                         int* __restrict__ counts, int m0) {
    int t = blockIdx.x * blockDim.x + threadIdx.x;     // 0 .. NTASKH-1 (exact)
    int slot = blockIdx.y;
    int pr = m0 + slot;
    int phase = pr / 12, m = pr % 12;
    int c = t >> 1, h = t & 1;

    int w, dw, dv, tA, tB;
    if (c < 3840) {                     // y-face: yi in 0..14, z in 0..63, q in 0..3
        int q = c & 3, r = c >> 2;
        int yi = r >> 6, z = r & 63;
        int y = 8 * yi + 7;
        w = (z * 128 + y) * 4 + q;
        dw = 4; dv = WW;
        tA = ((z >> 3) * 16 + yi) * MAXC;
        tB = tA + MAXC;
    } else {                            // z-face: zi in 0..6, y in 0..127, q in 0..3
        int tt = c - 3840;
        int q = tt & 3, r = tt >> 2;
        int zi = r >> 7, y = r & 127;
        int z = 8 * zi + 7;
        w = (z * 128 + y) * 4 + q;
        dw = 512; dv = HH * WW;
        tA = (zi * 16 + (y >> 3)) * MAXC;
        tB = tA + 16 * MAXC;
    }

    uint32_t a16 = (ld_word(maskW, erodW, phase, m, w) >> (16 * h)) & 0xFFFFu;
    uint32_t ov = 0;
    if (a16)
        ov = a16 & ((ld_word(maskW, erodW, phase, m, w + dw) >> (16 * h)) & 0xFFFFu);
    uint32_t st = ov & ~(ov << 1);

    const uint16_t* C16 = C16all + (size_t)slot * NVOX;
    int i0 = (w << 5) + 16 * h;
    int ca = -1, cb = -1, p0 = -1;
    if (st) {
        p0 = __ffs(st) - 1;
        ca = tA + C16[i0 + p0];
        cb = tB + C16[i0 + p0 + dv];
    }
    // cross-lane dedup seed: previous lane's first pair
    int la = __shfl_up(ca, 1);
    int lb = __shfl_up(cb, 1);
    if ((threadIdx.x & 63) == 0) { la = -1; lb = -1; }
    if (!st) return;

    int* P = Pall + (size_t)slot * NODE_STRIDE;
    int* dec = (phase < 2) ? &counts[pr] : (int*)0;
    while (st) {
        int p = __ffs(st) - 1; st &= st - 1;
        int xa, xb;
        if (p == p0) { xa = ca; xb = cb; }
        else { xa = tA + C16[i0 + p]; xb = tB + C16[i0 + p + dv]; }   // L1-hot lines
        if (xa != la || xb != lb) { uf_union(P, xa, xb, dec); la = xa; lb = xb; }
    }
}

// flatten allocated component entries (phase-2 slots) so finds become 1 load.
__global__ void k_flat(int* __restrict__ Pall, const int* __restrict__ tcount, int slot0) {
    int slot = slot0 + blockIdx.y;
    int tile = blockIdx.x;
    int* P = Pall + (size_t)slot * NODE_STRIDE;
    int lc = tcount[slot * NTILE + tile];
    for (int k = threadIdx.x; k < lc; k += blockDim.x) {
        int id = tile * MAXC + k;
        P[id] = uf_find_ro(P, id);
    }
    if (tile == 0 && threadIdx.x == 0) P[VNODE] = uf_find_ro(P, VNODE);
}

// phase 2: cavity volume = bg voxels whose component != border component.
__global__ void k_count2(const uint32_t* __restrict__ maskW,
                         const uint16_t* __restrict__ C16all, const int* __restrict__ Pall,
                         int* __restrict__ counts, int pr0, int slot0) {
    __shared__ int sRootV;
    int w = blockIdx.x * blockDim.x + threadIdx.x;
    int slot = slot0 + blockIdx.y;
    int pr = pr0 + blockIdx.y;
    int m = pr % 12;
    const uint16_t* C16 = C16all + (size_t)slot * NVOX;
    const int* P = Pall + (size_t)slot * NODE_STRIDE;
    if (threadIdx.x == 0) sRootV = P[VNODE];           // flattened
    __syncthreads();
    int i0 = w << 5;
    // independent loads up-front: mask word + C16 row-line warm (all words live)
    uint32_t a = ~maskW[m * NWRD + w];
    int c0 = C16[i0];
    int cnt = 0;
    if (a) {
        int tA = tile_of_w(w) * MAXC;
        int rootV = sRootV;
        uint32_t st = a & ~(a << 1);
        while (st) {
            int p = __ffs(st) - 1; st &= st - 1;
            uint32_t run = a >> p;
            uint32_t inv = ~run;
            int len = inv ? (__ffs(inv) - 1) : (32 - p);
            int id = (p == 0) ? c0 : (int)C16[i0 + p];     // L1-hot line
            if (P[tA + id] != rootV) cnt += len;           // flattened: 1 load
        }
    }
    for (int off = 32; off; off >>= 1) cnt += __shfl_down(cnt, off);
    if ((threadIdx.x & 63) == 0 && cnt) atomicAdd(&counts[pr], cnt);
}

__global__ void k_loss(const int* __restrict__ counts, float* __restrict__ out) {
    if (threadIdx.x != 0 || blockIdx.x != 0) return;
    float acc = 0.f;
    for (int m = 0; m < 6; ++m) {
        int pb0 = counts[m],      pbe = counts[12 + m],      pcv = counts[24 + m];
        int tb0 = counts[6 + m],  tbe = counts[12 + 6 + m],  tcv = counts[24 + 6 + m];
        int pb1 = max(0, pb0 - pbe), tb1 = max(0, tb0 - tbe);
        int pb2 = pcv / 100, tb2 = tcv / 100;
        acc += fabsf((float)(pb0 - tb0)) + fabsf((float)(pb1 - tb1)) + fabsf((float)(pb2 - tb2));
    }
    out[0] = 0.1f * acc / 6.0f;
}

// ---------------- launch ----------------
extern "C" void kernel_launch(void* const* d_in, const int* in_sizes, int n_in,
                              void* d_out, int out_size, void* d_ws, size_t ws_size,
                              hipStream_t stream) {
    const float* pred = (const float*)d_in[0];
    const int* tgt = (const int*)d_in[1];
    float* out = (float*)d_out;

    uint8_t* ws = (uint8_t*)d_ws;
    uint32_t* maskW = (uint32_t*)ws;
    size_t off = (size_t)NMASK * NWRD * 4;                 // 1.5 MB
    uint32_t* erodW = (uint32_t*)(ws + off);
    off += (size_t)NMASK * NWRD * 4;                       // +1.5 MB
    int* counts = (int*)(ws + off);
    off += 256;
    int* tcount = (int*)(ws + off);
    off += (size_t)NPROB * NTILE * 4;                      // 18 KB
    off = (off + 255) & ~(size_t)255;

    size_t avail = ws_size > off ? ws_size - off : 0;
    size_t slot_bytes = (size_t)NVOX * 2 + (size_t)NODE_STRIDE * 4;  // ~4.2 MB
    int PB = (int)(avail / slot_bytes);
    if (PB > NPROB) PB = NPROB;
    if (PB < 1) PB = 1;

    uint16_t* C16all = (uint16_t*)(ws + off);
    int* Pall = (int*)(ws + off + (size_t)PB * NVOX * 2);

    k_masks2<<<dim3((BATCH * NVOX) / 256), 256, 0, stream>>>(pred, tgt, maskW, counts);
    k_erode<<<dim3((NMASK * NWRD) / 256), 256, 0, stream>>>(maskW, erodW);

    for (int m0 = 0; m0 < NPROB; m0 += PB) {
        int mb = PB < (NPROB - m0) ? PB : (NPROB - m0);
        k_local <<<dim3(NTILE, mb), 512, 0, stream>>>(maskW, erodW, C16all, Pall,
                                                      counts, tcount, m0);
        k_bmerge<<<dim3(NTASKH / 256, mb), 256, 0, stream>>>(maskW, erodW, C16all,
                                                             Pall, counts, m0);
        int lo2 = m0 > 24 ? m0 : 24;
        int n2 = (m0 + mb) - lo2;
        if (n2 > 0) {
            k_flat  <<<dim3(NTILE, n2), 256, 0, stream>>>(Pall, tcount, lo2 - m0);
            k_count2<<<dim3(NWRD / 256, n2), 256, 0, stream>>>(maskW, C16all, Pall, counts,
                                                               lo2, lo2 - m0);
        }
    }

    k_loss<<<1, 64, 0, stream>>>(counts, out);
}

// Round 14
// 273.440 us; speedup vs baseline: 1.0916x; 1.0903x over previous
//
#include <hip/hip_runtime.h>
#include <stdint.h>

#define DD 64
#define HH 128
#define WW 128
#define NVOX (DD * HH * WW)      // 1<<20
#define NWRD (NVOX / 32)         // 32768 words per mask
#define BATCH 2
#define NCLS 4
#define NMASK 12                 // 6 pred then 6 target
#define NPROB 36                 // phase*12 + m ; phase: 0=mask 1=eroded 2=background
#define NTILE 128                // (HH/8)*(DD/8) tiles of 128x8x8 voxels
#define MAXC 4096                // max components per 8192-voxel tile (checkerboard bound)
#define VNODE (NTILE * MAXC)     // virtual border node id = 524288
#define NODE_STRIDE (VNODE + 64) // ints per component-parent slot
#define NTASKW 7424              // face word-crossings per problem: 3840 y + 3584 z

// ---------------- global lock-free union-find (on component ids) --------
__device__ __forceinline__ int uf_find(int* P, int x) {
    while (true) {
        int p = P[x];
        if (p == x) return x;
        int gp = P[p];
        if (gp != p) P[x] = gp;   // path halving (benign race; never demotes a root)
        x = gp;
    }
}
__device__ __forceinline__ int uf_find_ro(const int* P, int x) {
    int p;
    while ((p = P[x]) != x) x = p;
    return x;
}
// counting union: each successful CAS demotes exactly one root -> dec.
__device__ __forceinline__ void uf_union(int* P, int a, int b, int* dec) {
    while (true) {
        a = uf_find(P, a);
        b = uf_find(P, b);
        if (a == b) return;
        int lo = a < b ? a : b;
        int hi = a < b ? b : a;
        int old = atomicCAS(&P[hi], hi, lo);
        if (old == hi) { if (dec) atomicSub(dec, 1); return; }
        a = lo; b = old;
    }
}

// ---------------- LDS union-find on half-word run heads (swizzled) ------
#define SW(v) ((v) + ((v) >> 5))
__device__ __forceinline__ int lfind(int* lp, int x) {
    while (true) {
        int p = lp[SW(x)];
        if (p == x) return x;
        int gp = lp[SW(p)];
        if (gp != p) lp[SW(x)] = gp;
        x = gp;
    }
}
__device__ __forceinline__ void lunion(int* lp, int a, int b) {
    while (true) {
        a = lfind(lp, a);
        b = lfind(lp, b);
        if (a == b) return;
        int lo = a < b ? a : b;
        int hi = a < b ? b : a;
        int old = atomicCAS(&lp[SW(hi)], hi, lo);
        if (old == hi) return;
        a = lo; b = old;
    }
}
// resolve a head to its component's compact id (root entries hold -k-1).
__device__ __forceinline__ int lresolve(const int* lp, int h) {
    int v = lp[SW(h)];
    while (v >= 0) v = lp[SW(v)];
    return -v - 1;
}
// start bit of the 1-run of w containing set bit p (works for 16/32-bit w)
__device__ __forceinline__ int run_head(uint32_t w, int p) {
    uint32_t below = ~w & ((1u << p) - 1u);
    return below ? (32 - __clz((int)below)) : 0;
}

// word loader for problem (phase, m)
__device__ __forceinline__ uint32_t ld_word(const uint32_t* __restrict__ maskW,
                                            const uint32_t* __restrict__ erodW,
                                            int phase, int m, int w) {
    if (phase == 0) return maskW[m * NWRD + w];
    if (phase == 1) return erodW[m * NWRD + w];
    return ~maskW[m * NWRD + w];
}

// tile index of word w (tz*16 + ty)
__device__ __forceinline__ int tile_of_w(int w) {
    int z = w >> 9, y = (w >> 2) & 127;
    return (z >> 3) * 16 + (y >> 3);
}

// ---------------- kernels ----------------

// Build 12 bitpacked masks via ballot; zero counters.
__global__ void k_masks2(const float* __restrict__ pred, const int* __restrict__ tgt,
                         uint32_t* __restrict__ maskW, int* __restrict__ counts) {
    int tid = blockIdx.x * blockDim.x + threadIdx.x;   // 0 .. BATCH*NVOX-1
    if (tid < 64) counts[tid] = 0;
    int b = tid >> 20;
    int i = tid & (NVOX - 1);
    const float* p = pred + (size_t)b * NCLS * NVOX + i;
    float x0 = p[0], x1 = p[NVOX], x2 = p[2 * NVOX], x3 = p[3 * NVOX];
    float mx = fmaxf(fmaxf(x0, x1), fmaxf(x2, x3));
    float e0 = __expf(x0 - mx), e1 = __expf(x1 - mx), e2 = __expf(x2 - mx), e3 = __expf(x3 - mx);
    float S = e0 + e1 + e2 + e3;
    int t = tgt[(size_t)b * NVOX + i];
    int lane = threadIdx.x & 63;
    int wbase = i >> 5;
    float ev[3] = {e1, e2, e3};
    for (int c = 0; c < 3; ++c) {
        unsigned long long bal = __ballot(ev[c] / S > 0.5f);
        uint32_t* M = maskW + (size_t)(b * 3 + c) * NWRD;
        if (lane == 0)  M[wbase] = (uint32_t)bal;
        if (lane == 32) M[wbase] = (uint32_t)(bal >> 32);
        unsigned long long balT = __ballot(t == c + 1);
        uint32_t* MT = maskW + (size_t)(6 + b * 3 + c) * NWRD;
        if (lane == 0)  MT[wbase] = (uint32_t)balT;
        if (lane == 32) MT[wbase] = (uint32_t)(balT >> 32);
    }
}

// 6-conn binary erosion, border_value=0, bitwise.
__global__ void k_erode(const uint32_t* __restrict__ maskW, uint32_t* __restrict__ erodW) {
    int tid = blockIdx.x * blockDim.x + threadIdx.x;   // 0 .. 12*NWRD-1
    int m = tid / NWRD;
    int w = tid - m * NWRD;
    const uint32_t* M = maskW + (size_t)m * NWRD;
    int z = w >> 9, y = (w >> 2) & 127, q = w & 3;
    uint32_t a = M[w];
    uint32_t xl = (a << 1) | (q ? (M[w - 1] >> 31) : 0u);
    uint32_t xr = (a >> 1) | (q < 3 ? (M[w + 1] << 31) : 0u);
    uint32_t ym = (y > 0)   ? M[w - 4]   : 0u;
    uint32_t yp = (y < 127) ? M[w + 4]   : 0u;
    uint32_t zm = (z > 0)   ? M[w - 512] : 0u;
    uint32_t zp = (z < 63)  ? M[w + 512] : 0u;
    erodW[tid] = a & xl & xr & ym & yp & zm & zp;
}

// Tile-local CC (128x8x8 per block, 512 threads = one per 16-bit half-word):
// head-only LDS union-find, compact id allocation, demand-driven C16 emit,
// phase-2 border pre-link to VNODE. Neighbor words (aprev/by/bz) are all
// intra-tile -> served from the LDS word cache aw[256] instead of global.
__global__ void k_local(const uint32_t* __restrict__ maskW, const uint32_t* __restrict__ erodW,
                        uint16_t* __restrict__ C16all, int* __restrict__ Pall,
                        int* __restrict__ counts, int* __restrict__ tcount, int m0) {
    __shared__ int lp[8448];         // swizzled; only half-run-head entries live
    __shared__ uint32_t aw[256];     // per-tile word cache
    __shared__ int lcount;
    int slot = blockIdx.y;
    int pr = m0 + slot;
    int phase = pr / 12, m = pr % 12;
    uint16_t* C16 = C16all + (size_t)slot * NVOX;
    int* P = Pall + (size_t)slot * NODE_STRIDE;
    int tile = blockIdx.x;                         // 0..127
    int tz = tile >> 4, ty = tile & 15;
    int t2 = threadIdx.x;                          // 0..511 : half-word index
    int wl = t2 >> 1;                              // local word 0..255
    int h  = t2 & 1;                               // half within word
    int zl = wl >> 5, yl = (wl >> 2) & 7, q = wl & 3;
    int gw = ((tz * 8 + zl) * 128 + (ty * 8 + yl)) * 4 + q;
    uint32_t afull = ld_word(maskW, erodW, phase, m, gw);  // only global load
    if (h == 0) aw[wl] = afull;
    uint32_t a16 = (afull >> (16 * h)) & 0xFFFFu;
    if (t2 == 0) lcount = 0;
    if (blockIdx.x == 0 && t2 == 0) P[VNODE] = VNODE;   // virtual border node

    // s1: init half-run-head entries only
    int lbase = t2 << 4;
    uint32_t heads = a16 & ~(a16 << 1) & 0xFFFFu;
    {
        uint32_t st = heads;
        while (st) { int p = __ffs(st) - 1; st &= st - 1; lp[SW(lbase + p)] = lbase + p; }
    }
    __syncthreads();                                // lp heads + aw visible

    // s2: intra-tile unions (half-head nodes; neighbors from LDS word cache)
    if (a16) {
        if (a16 & 1u) {            // x link to previous half / previous word
            if (h == 1) {
                uint32_t lo16 = afull & 0xFFFFu;
                if (lo16 >> 15) lunion(lp, lbase, lbase - 16 + run_head(lo16, 15));
            } else if (q) {
                uint32_t hi16 = aw[wl - 1] >> 16;
                if (hi16 >> 15) lunion(lp, lbase, lbase - 16 + run_head(hi16, 15));
            }
        }
        if (yl < 7) {
            uint32_t by = (aw[wl + 4] >> (16 * h)) & 0xFFFFu;
            uint32_t ov = a16 & by;
            uint32_t st = ov & ~(ov << 1);
            int la = -1, lb = -1;
            while (st) {
                int p = __ffs(st) - 1; st &= st - 1;
                int ha = lbase + run_head(a16, p);
                int hb = lbase + 128 + run_head(by, p);     // word+4 -> +8 halves
                if (ha != la || hb != lb) { lunion(lp, ha, hb); la = ha; lb = hb; }
            }
        }
        if (zl < 7) {
            uint32_t bz = (aw[wl + 32] >> (16 * h)) & 0xFFFFu;
            uint32_t ov = a16 & bz;
            uint32_t st = ov & ~(ov << 1);
            int la = -1, lb = -1;
            while (st) {
                int p = __ffs(st) - 1; st &= st - 1;
                int ha = lbase + run_head(a16, p);
                int hb = lbase + 1024 + run_head(bz, p);    // word+32 -> +64 halves
                if (ha != la || hb != lb) { lunion(lp, ha, hb); la = ha; lb = hb; }
            }
        }
    }
    __syncthreads();

    // s3: root heads allocate compact ids (root entry := -k-1)
    int tileBase = tile * MAXC;
    {
        uint32_t st = heads;
        while (st) {
            int p = __ffs(st) - 1; st &= st - 1;
            int hh = lbase + p;
            if (lp[SW(hh)] == hh) {
                int k = atomicAdd(&lcount, 1);
                lp[SW(hh)] = -k - 1;
                P[tileBase + k] = tileBase + k;    // sparse parent init
            }
        }
    }
    __syncthreads();

    if (t2 == 0) {
        tcount[slot * NTILE + tile] = lcount;
        if (phase < 2 && lcount) atomicAdd(&counts[pr], lcount);
    }

    // s4: demand-driven emit + phase-2 VNODE pre-link.
    bool faceRow = (yl == 0 || yl == 7 || zl == 0 || zl == 7);
    if (a16 && (phase == 2 || faceRow)) {
        int i0 = (gw << 5) + 16 * h;
        int gz = tz * 8 + zl, gy = ty * 8 + yl;
        bool bordRow = (phase == 2) && (gz == 0 || gz == 63 || gy == 0 || gy == 127);
        if (faceRow && a16 == 0xFFFFu) {
            int id = lresolve(lp, lbase);
            uint32_t pk = (uint32_t)id * 0x10001u;
            uint4 v = make_uint4(pk, pk, pk, pk);
            uint4* dst = (uint4*)(C16 + i0);
            dst[0] = v; dst[1] = v;
            if (phase == 2 && (bordRow || (q == 0 && h == 0) || (q == 3 && h == 1)))
                P[tileBase + id] = VNODE;
        } else {
            int htop = (a16 >> 15) ? run_head(a16, 15) : -1;
            uint32_t st = heads;
            while (st) {
                int p = __ffs(st) - 1; st &= st - 1;
                int id = lresolve(lp, lbase + p);
                C16[i0 + p] = (uint16_t)id;
                if (faceRow) {
                    uint32_t run = a16 >> p;
                    int len = __ffs(~run) - 1;       // run < 2^16 so ~run != 0
                    for (int j = 1; j < len; ++j) C16[i0 + p + j] = (uint16_t)id;
                }
                if (phase == 2 &&
                    (bordRow || (q == 0 && h == 0 && p == 0) ||
                     (q == 3 && h == 1 && p == htop)))
                    P[tileBase + id] = VNODE;
            }
        }
    }
}

// face merges: one thread per face WORD-crossing (r9/r11 structure — the
// empirically best shape) with strictly conditional loads + shfl dedup.
// Cross-word duplicate unions are idempotent and exactly counted.
__global__ void k_bmerge(const uint32_t* __restrict__ maskW, const uint32_t* __restrict__ erodW,
                         const uint16_t* __restrict__ C16all, int* __restrict__ Pall,
                         int* __restrict__ counts, int m0) {
    int t = blockIdx.x * blockDim.x + threadIdx.x;     // 0 .. NTASKW-1
    int slot = blockIdx.y;
    int pr = m0 + slot;
    int phase = pr / 12, m = pr % 12;
    bool act = (t < NTASKW);

    int w = 0, dw = 4, dv = WW, tA = 0, tB = 0;
    if (act) {
        if (t < 3840) {                 // y-face: yi in 0..14, z in 0..63, q in 0..3
            int q = t & 3, r = t >> 2;
            int yi = r >> 6, z = r & 63;
            int y = 8 * yi + 7;
            w = (z * 128 + y) * 4 + q;
            dw = 4; dv = WW;
            tA = ((z >> 3) * 16 + yi) * MAXC;
            tB = tA + MAXC;
        } else {                        // z-face: zi in 0..6, y in 0..127, q in 0..3
            int tt = t - 3840;
            int q = tt & 3, r = tt >> 2;
            int zi = r >> 7, y = r & 127;
            int z = 8 * zi + 7;
            w = (z * 128 + y) * 4 + q;
            dw = 512; dv = HH * WW;
            tA = (zi * 16 + (y >> 3)) * MAXC;
            tB = tA + 16 * MAXC;
        }
    }

    uint32_t ov = 0;
    if (act) {
        uint32_t a = ld_word(maskW, erodW, phase, m, w);
        if (a) {
            uint32_t b = ld_word(maskW, erodW, phase, m, w + dw);
            ov = a & b;
        }
    }

    const uint16_t* C16 = C16all + (size_t)slot * NVOX;
    int* P = Pall + (size_t)slot * NODE_STRIDE;
    int* dec = (phase < 2) ? &counts[pr] : (int*)0;
    int i0 = w << 5;
    uint32_t st = ov & ~(ov << 1);

    // first head pair (sentinel -1 for inactive lanes)
    int ca = -1, cb = -1, p0 = -1;
    if (st) {
        p0 = __ffs(st) - 1;
        ca = tA + C16[i0 + p0];
        cb = tB + C16[i0 + p0 + dv];
    }
    // cross-lane dedup seed: previous lane's first pair
    int la = __shfl_up(ca, 1);
    int lb = __shfl_up(cb, 1);
    if ((threadIdx.x & 63) == 0) { la = -1; lb = -1; }

    while (st) {
        int p = __ffs(st) - 1; st &= st - 1;
        int xa, xb;
        if (p == p0) { xa = ca; xb = cb; }
        else { xa = tA + C16[i0 + p]; xb = tB + C16[i0 + p + dv]; }
        if (xa != la || xb != lb) { uf_union(P, xa, xb, dec); la = xa; lb = xb; }
    }
}

// flatten allocated component entries (phase-2 slots) so finds become 1 load.
__global__ void k_flat(int* __restrict__ Pall, const int* __restrict__ tcount, int slot0) {
    int slot = slot0 + blockIdx.y;
    int tile = blockIdx.x;
    int* P = Pall + (size_t)slot * NODE_STRIDE;
    int lc = tcount[slot * NTILE + tile];
    for (int k = threadIdx.x; k < lc; k += blockDim.x) {
        int id = tile * MAXC + k;
        P[id] = uf_find_ro(P, id);
    }
    if (tile == 0 && threadIdx.x == 0) P[VNODE] = uf_find_ro(P, VNODE);
}

// phase 2: cavity volume = bg voxels whose component != border component.
__global__ void k_count2(const uint32_t* __restrict__ maskW,
                         const uint16_t* __restrict__ C16all, const int* __restrict__ Pall,
                         int* __restrict__ counts, int pr0, int slot0) {
    __shared__ int sRootV;
    int w = blockIdx.x * blockDim.x + threadIdx.x;
    int slot = slot0 + blockIdx.y;
    int pr = pr0 + blockIdx.y;
    int m = pr % 12;
    const uint16_t* C16 = C16all + (size_t)slot * NVOX;
    const int* P = Pall + (size_t)slot * NODE_STRIDE;
    if (threadIdx.x == 0) sRootV = P[VNODE];           // flattened
    __syncthreads();
    int i0 = w << 5;
    // independent loads up-front: mask word + C16 row-line warm (all words live)
    uint32_t a = ~maskW[m * NWRD + w];
    int c0 = C16[i0];
    int cnt = 0;
    if (a) {
        int tA = tile_of_w(w) * MAXC;
        int rootV = sRootV;
        uint32_t st = a & ~(a << 1);
        while (st) {
            int p = __ffs(st) - 1; st &= st - 1;
            uint32_t run = a >> p;
            uint32_t inv = ~run;
            int len = inv ? (__ffs(inv) - 1) : (32 - p);
            int id = (p == 0) ? c0 : (int)C16[i0 + p];     // L1-hot line
            if (P[tA + id] != rootV) cnt += len;           // flattened: 1 load
        }
    }
    for (int off = 32; off; off >>= 1) cnt += __shfl_down(cnt, off);
    if ((threadIdx.x & 63) == 0 && cnt) atomicAdd(&counts[pr], cnt);
}

__global__ void k_loss(const int* __restrict__ counts, float* __restrict__ out) {
    if (threadIdx.x != 0 || blockIdx.x != 0) return;
    float acc = 0.f;
    for (int m = 0; m < 6; ++m) {
        int pb0 = counts[m],      pbe = counts[12 + m],      pcv = counts[24 + m];
        int tb0 = counts[6 + m],  tbe = counts[12 + 6 + m],  tcv = counts[24 + 6 + m];
        int pb1 = max(0, pb0 - pbe), tb1 = max(0, tb0 - tbe);
        int pb2 = pcv / 100, tb2 = tcv / 100;
        acc += fabsf((float)(pb0 - tb0)) + fabsf((float)(pb1 - tb1)) + fabsf((float)(pb2 - tb2));
    }
    out[0] = 0.1f * acc / 6.0f;
}

// ---------------- launch ----------------
extern "C" void kernel_launch(void* const* d_in, const int* in_sizes, int n_in,
                              void* d_out, int out_size, void* d_ws, size_t ws_size,
                              hipStream_t stream) {
    const float* pred = (const float*)d_in[0];
    const int* tgt = (const int*)d_in[1];
    float* out = (float*)d_out;

    uint8_t* ws = (uint8_t*)d_ws;
    uint32_t* maskW = (uint32_t*)ws;
    size_t off = (size_t)NMASK * NWRD * 4;                 // 1.5 MB
    uint32_t* erodW = (uint32_t*)(ws + off);
    off += (size_t)NMASK * NWRD * 4;                       // +1.5 MB
    int* counts = (int*)(ws + off);
    off += 256;
    int* tcount = (int*)(ws + off);
    off += (size_t)NPROB * NTILE * 4;                      // 18 KB
    off = (off + 255) & ~(size_t)255;

    size_t avail = ws_size > off ? ws_size - off : 0;
    size_t slot_bytes = (size_t)NVOX * 2 + (size_t)NODE_STRIDE * 4;  // ~4.2 MB
    int PB = (int)(avail / slot_bytes);
    if (PB > NPROB) PB = NPROB;
    if (PB < 1) PB = 1;

    uint16_t* C16all = (uint16_t*)(ws + off);
    int* Pall = (int*)(ws + off + (size_t)PB * NVOX * 2);

    k_masks2<<<dim3((BATCH * NVOX) / 256), 256, 0, stream>>>(pred, tgt, maskW, counts);
    k_erode<<<dim3((NMASK * NWRD) / 256), 256, 0, stream>>>(maskW, erodW);

    for (int m0 = 0; m0 < NPROB; m0 += PB) {
        int mb = PB < (NPROB - m0) ? PB : (NPROB - m0);
        k_local <<<dim3(NTILE, mb), 512, 0, stream>>>(maskW, erodW, C16all, Pall,
                                                      counts, tcount, m0);
        k_bmerge<<<dim3((NTASKW + 255) / 256, mb), 256, 0, stream>>>(maskW, erodW, C16all,
                                                                     Pall, counts, m0);
        int lo2 = m0 > 24 ? m0 : 24;
        int n2 = (m0 + mb) - lo2;
        if (n2 > 0) {
            k_flat  <<<dim3(NTILE, n2), 256, 0, stream>>>(Pall, tcount, lo2 - m0);
            k_count2<<<dim3(NWRD / 256, n2), 256, 0, stream>>>(maskW, C16all, Pall, counts,
                                                               lo2, lo2 - m0);
        }
    }

    k_loss<<<1, 64, 0, stream>>>(counts, out);
}